// Round 7
// baseline (3815.096 us; speedup 1.0000x reference)
//
#include <hip/hip_runtime.h>

#define NB 32
#define NN 256
#define NI 16
#define NO 16
#define NC 64
#define NH 64
#define NE 4096
#define FC1_N 4096

__device__ __forceinline__ float sigmoidf_(float x){ return 1.0f/(1.0f+__expf(-x)); }
__device__ __forceinline__ float tanhf_(float x){
  float e = __expf(2.0f*x);
  return 1.0f - 2.0f/(e+1.0f);
}

// async global->LDS, 16B per lane (lane i lands at ldsbase + i*16)
__device__ __forceinline__ void gload16(const void* g, void* l){
  __builtin_amdgcn_global_load_lds((const __attribute__((address_space(1))) void*)g,
                                   (__attribute__((address_space(3))) void*)l, 16, 0, 0);
}

// ---- runtime dtype detection ------------------------------------------------
__global__ void k_detect(const unsigned char* __restrict__ m8, const int* __restrict__ ei, int* flags){
  int t = blockIdx.x*256 + threadIdx.x;              // 32768 threads
  unsigned a = (unsigned)m8[t*4+1] | (unsigned)m8[t*4+2] | (unsigned)m8[t*4+3];
  if (__any(a != 0) && (threadIdx.x & 63) == 0) atomicOr(&flags[0], 1);
  unsigned b = 0;
  if (t < 4096) b = (unsigned)ei[2*t+1];
  if (__any(b != 0) && (threadIdx.x & 63) == 0) atomicOr(&flags[1], 1);
}

// ---- mask -------------------------------------------------------------------
__global__ void k_mask(const float* __restrict__ data, const unsigned char* __restrict__ m8,
                       const int* __restrict__ flags, float* __restrict__ dm){
  int i = blockIdx.x*256 + threadIdx.x;              // 131072
  int mv = flags[0] ? (int)m8[i] : ((const int*)m8)[i];
  dm[i] = mv ? data[i] : 0.0f;
}

__device__ __forceinline__ int edge_src(const int* ei, const int* flags, int e){
  return flags[1] ? ei[e] : ei[2*e];
}
__device__ __forceinline__ int edge_dst(const int* ei, const int* flags, int e){
  return flags[1] ? ei[NE + e] : ei[2*(NE + e)];
}

// ---- GCN graph prep: zero wadj, degree, dinv, weighted adjacency (one block) --
__global__ __launch_bounds__(256) void k_graph(const int* __restrict__ ei, const int* __restrict__ flags,
                                               float* wadj){
  int t = threadIdx.x;
  float4 z = {0.f,0.f,0.f,0.f};
  for (int x = t; x < 16384; x += 256) ((float4*)wadj)[x] = z;
  __shared__ float degs[NN];
  __shared__ float dls[NN];
  degs[t] = 0.f;
  __syncthreads();
  for (int e = t; e < NE; e += 256) atomicAdd(&degs[edge_dst(ei, flags, e)], 1.0f);
  __syncthreads();
  float di = rsqrtf(degs[t] + 2.0f);
  dls[t] = di;
  atomicAdd(&wadj[t*NN + t], 2.0f*di*di);
  __syncthreads();
  for (int e = t; e < NE; e += 256){
    int s = edge_src(ei, flags, e), d = edge_dst(ei, flags, e);
    atomicAdd(&wadj[d*NN + s], dls[s]*dls[d]);
  }
}

// ---- xw = x @ gcn_w ----------------------------------------------------------
__global__ void k_xw(const float* __restrict__ dm, const float* __restrict__ gw, float* __restrict__ xw){
  int idx = blockIdx.x*256 + threadIdx.x;            // 524288
  int c = idx & 63, n = (idx>>6) & 255, b = idx>>14;
  const float* dmb = dm + b*NI*NN;
  float a = 0.f;
  #pragma unroll
  for (int i=0;i<NI;i++) a += dmb[i*NN + n]*gw[i*NC + c];
  xw[idx] = a;
}

// ---- h = relu(W_adj @ xw + b) -------------------------------------------------
__global__ void k_agg(const float* __restrict__ wadj, const float* __restrict__ xw,
                      const float* __restrict__ gb, float* __restrict__ h){
  int idx = blockIdx.x*256 + threadIdx.x;            // 524288
  int c = idx & 63, n = (idx>>6) & 255, b = idx>>14;
  const float* wr = wadj + n*NN;
  const float* xb = xw + b*NN*NC + c;
  float a = gb[c];
  #pragma unroll 4
  for (int m=0;m<NN;m++) a += wr[m]*xb[m*NC];
  h[idx] = fmaxf(a, 0.0f);
}

// ---- q,k projections, spatial (blocks<2048) + temporal fused -------------------
__global__ void k_qk2(const float* __restrict__ hb, const float* __restrict__ rnn,
    const float* __restrict__ saqw, const float* __restrict__ saqb,
    const float* __restrict__ sakw, const float* __restrict__ sakb,
    const float* __restrict__ taqw, const float* __restrict__ taqb,
    const float* __restrict__ takw, const float* __restrict__ takb,
    float* __restrict__ qb, float* __restrict__ kb, float* __restrict__ qt, float* __restrict__ kt){
  int bid = blockIdx.x;
  const float *src, *qw, *qbias, *kw, *kbias; float *qo, *ko;
  if (bid < 2048){ src=hb; qw=saqw; qbias=saqb; kw=sakw; kbias=sakb; qo=qb; ko=kb; }
  else { bid -= 2048; src=rnn; qw=taqw; qbias=taqb; kw=takw; kbias=takb; qo=qt; ko=kt; }
  int idx = bid*256 + threadIdx.x;
  int c = idx & 63;
  const float* hr = src + (idx>>6)*NC;
  float aq = qbias[c], ak = kbias[c];
  #pragma unroll 8
  for (int cc=0; cc<NC; cc++){ float hv = hr[cc]; aq += hv*qw[cc*NC + c]; ak += hv*kw[cc*NC + c]; }
  qo[idx] = aq; ko[idx] = ak;
}

// ---- fused attention pair; REP = diagnostic idempotent repeat ------------------
template<int REP>
__global__ __launch_bounds__(256) void k_attn2(const float* __restrict__ qb, const float* __restrict__ kb,
    const float* __restrict__ hb, const float* __restrict__ qt, const float* __restrict__ kt,
    const float* __restrict__ rnn, float* __restrict__ out_sa, float* __restrict__ out_ra){
  int bidx = blockIdx.x;
  const float *q, *kmat, *v; float* outp;
  if (bidx < 1024){ q=qb; kmat=kb; v=hb; outp=out_sa; }
  else { bidx -= 1024; q=qt; kmat=kt; v=rnn; outp=out_ra; }
  int b = bidx >> 5, n0 = (bidx & 31)*8;
  int t = threadIdx.x;
  const float scale = 0.0625f;
  __shared__ __align__(16) float qs[8][64];
  __shared__ float S[8][256];
  for (int rep=0; rep<REP; rep++){
    #pragma unroll
    for (int rp2=0; rp2<2; rp2++){
      int j = rp2*256 + t; int r = j>>6, c = j&63;
      qs[r][c] = q[((b<<8) + n0 + r)*NC + c];
    }
    __syncthreads();
    float4 kr[16];
    const float4* kp = (const float4*)(kmat + ((b<<8) + t)*NC);
    #pragma unroll
    for (int i=0;i<16;i++) kr[i] = kp[i];
    #pragma unroll
    for (int r=0;r<8;r++){
      const float4* q4 = (const float4*)qs[r];
      float s = 0.f;
      #pragma unroll
      for (int i=0;i<16;i++){ float4 a=q4[i], bb=kr[i]; s += a.x*bb.x + a.y*bb.y + a.z*bb.z + a.w*bb.w; }
      S[r][t] = s*scale;
    }
    __syncthreads();
    {
      int g = t>>5, l = t&31;
      float vals[8];
      #pragma unroll
      for (int k2=0;k2<8;k2++) vals[k2] = S[g][l + (k2<<5)];
      float mx = vals[0];
      #pragma unroll
      for (int k2=1;k2<8;k2++) mx = fmaxf(mx, vals[k2]);
      #pragma unroll
      for (int off=16; off; off>>=1) mx = fmaxf(mx, __shfl_xor(mx, off));
      float sm = 0.f;
      #pragma unroll
      for (int k2=0;k2<8;k2++){ vals[k2] = __expf(vals[k2]-mx); sm += vals[k2]; }
      #pragma unroll
      for (int off=16; off; off>>=1) sm += __shfl_xor(sm, off);
      float rS = 1.0f/sm;
      #pragma unroll
      for (int k2=0;k2<8;k2++) S[g][l + (k2<<5)] = vals[k2]*rS;
    }
    __syncthreads();
    int c = t & 63, rp = t >> 6;
    const float* vp = v + (b<<8)*NC + c;
    float a0 = 0.f, a1 = 0.f;
    #pragma unroll 4
    for (int m=0;m<NN;m++){
      float vv = vp[m*NC];
      a0 += S[rp][m]*vv;
      a1 += S[rp+4][m]*vv;
    }
    outp[(((b<<6)+c)<<8) + n0 + rp]     = a0;
    outp[(((b<<6)+c)<<8) + n0 + rp + 4] = a1;
    __syncthreads();                                  // rep separator
  }
}

// ---- GRU (192-thread proven version); REP = diagnostic idempotent repeat -------
template<int REP>
__global__ __launch_bounds__(192) void k_gru(const float* __restrict__ dm,
        const float* __restrict__ wih, const float* __restrict__ bih,
        const float* __restrict__ whh, const float* __restrict__ bhh,
        float* __restrict__ rnn){
  int b = blockIdx.x, j = threadIdx.x;
  __shared__ __align__(16) float dmS[4096];
  __shared__ __align__(16) float hs[64];
  __shared__ float gh[192];
  __shared__ float gin[64];
  float wh[64];
  const float4* wr = (const float4*)(whh + j*NH);
  #pragma unroll
  for (int k4=0;k4<16;k4++){ float4 t4 = wr[k4]; wh[4*k4]=t4.x; wh[4*k4+1]=t4.y; wh[4*k4+2]=t4.z; wh[4*k4+3]=t4.w; }
  float wi[16];
  const float4* wir = (const float4*)(wih + j*NI);
  #pragma unroll
  for (int k4=0;k4<4;k4++){ float4 t4 = wir[k4]; wi[4*k4]=t4.x; wi[4*k4+1]=t4.y; wi[4*k4+2]=t4.z; wi[4*k4+3]=t4.w; }
  float bj = bhh[j], bij = bih[j];
  const float4* dmb4 = (const float4*)(dm + b*4096);
  for (int x = j; x < 1024; x += 192) ((float4*)dmS)[x] = dmb4[x];
  for (int rep=0; rep<REP; rep++){
    if (j < 64) hs[j] = 0.f;
    __syncthreads();
    for (int t=0;t<NN;t++){
      const float* xt = &dmS[t*16];
      float gival = bij;
      #pragma unroll
      for (int i=0;i<16;i++) gival += wi[i]*xt[i];
      float a0=0.f,a1=0.f,a2=0.f,a3=0.f;
      #pragma unroll
      for (int k4=0;k4<16;k4++){
        float4 hv = *(const float4*)&hs[4*k4];
        a0 += wh[4*k4+0]*hv.x; a1 += wh[4*k4+1]*hv.y; a2 += wh[4*k4+2]*hv.z; a3 += wh[4*k4+3]*hv.w;
      }
      float ghv = a0+a1+a2+a3+bj;
      if (j < 128) gh[j] = ghv + gival;
      else { gh[j] = ghv; gin[j-128] = gival; }
      __syncthreads();
      if (j < 64){
        float r  = sigmoidf_(gh[j]);
        float z  = sigmoidf_(gh[j+64]);
        float nn = tanhf_   (gin[j] + r*gh[j+128]);
        float hn = nn + z*(hs[j]-nn);
        rnn[(b*NN + t)*NH + j] = hn;
        hs[j] = hn;
      }
      __syncthreads();
    }
  }
}

// ---- E_T[32768][32]: transposed embed = concat([rnn_out, se]) ------------------
__global__ void k_embedT(const float* __restrict__ rnn, const float* __restrict__ h,
                         float* __restrict__ ET){
  int idx = blockIdx.x*256 + threadIdx.x;            // 1048576
  int bb = idx & 31, rr = idx >> 5;
  int n = rr >> 7, c = rr & 127;
  float v;
  if (c < 64) v = rnn[((bb<<8) + n)*NH + c];
  else { int f = (n<<6) + (c-64); v = h[(bb<<14) + ((f&255)<<6) + (f>>8)]; }
  ET[idx] = v;
}

// ---- fc GEMM: chunk 8 rows x 512 cols, dbuf LDS via gload_lds -------------------
// block 512 = 8 waves (2 col-waves x 4 batch-quarters); grid (8, K/KC).
// REP = diagnostic idempotent repeat (acc re-zeroed per rep).
template<int KC, int REP>
__global__ __launch_bounds__(512, 4) void k_fc(const float* __restrict__ W,
        const float* __restrict__ Ein, float* __restrict__ part){
  const int tid = threadIdx.x, lane = tid & 63, wv_ = tid >> 6;
  const int cw = wv_ & 1, bq = wv_ >> 1;
  const int c0 = blockIdx.x*512;
  const long k0 = (long)blockIdx.y*KC;
  __shared__ __align__(16) float wlds[2][8][512];    // 32 KB
  __shared__ __align__(16) float elds[2][256];       // 2 KB
  float acc[4][8];

  const int NCH = KC/8;
  #define STAGE_FC(ch, bf) { \
    const float* wsrc = W + (k0 + (long)(ch)*8)*FC1_N + c0; \
    gload16(wsrc + (long)wv_*FC1_N + lane*4,       &wlds[bf][wv_][0]); \
    gload16(wsrc + (long)wv_*FC1_N + 256 + lane*4, &wlds[bf][wv_][256]); \
    if (wv_ == 0) gload16(Ein + (k0 + (long)(ch)*8)*32 + lane*4, &elds[bf][0]); \
  }

  for (int rep=0; rep<REP; rep++){
    __syncthreads();                                  // protect LDS from prev rep readers
    #pragma unroll
    for (int c=0;c<4;c++)
      #pragma unroll
      for (int bb=0;bb<8;bb++) acc[c][bb]=0.f;
    STAGE_FC(0, 0)
    int cur = 0;
    for (int ch=0; ch<NCH; ch++){
      __syncthreads();                                // chunk ch ready (vmcnt drain)
      if (ch+1 < NCH) STAGE_FC(ch+1, cur^1)
      #pragma unroll
      for (int r=0;r<8;r++){
        float4 wv4 = *(const float4*)&wlds[cur][r][cw*256 + lane*4];
        float4 e0 = *(const float4*)&elds[cur][r*32 + bq*8];
        float4 e1 = *(const float4*)&elds[cur][r*32 + bq*8 + 4];
        float ev[8] = {e0.x,e0.y,e0.z,e0.w,e1.x,e1.y,e1.z,e1.w};
        #pragma unroll
        for (int bb=0;bb<8;bb++){
          acc[0][bb] += wv4.x*ev[bb];
          acc[1][bb] += wv4.y*ev[bb];
          acc[2][bb] += wv4.z*ev[bb];
          acc[3][bb] += wv4.w*ev[bb];
        }
      }
      cur ^= 1;
    }
  }
  float* pp = part + (long)blockIdx.y*131072 + (long)(bq*8)*FC1_N + c0 + cw*256 + lane*4;
  #pragma unroll
  for (int bb=0;bb<8;bb++){
    float4 o; o.x=acc[0][bb]; o.y=acc[1][bb]; o.z=acc[2][bb]; o.w=acc[3][bb];
    *(float4*)(pp + (long)bb*FC1_N) = o;
  }
  #undef STAGE_FC
}

// ---- reduce fc1 partials (128) + bias -> interT[4096][32] ----------------------
__global__ void k_red1(const float* __restrict__ part, const float* __restrict__ bias,
                       float* __restrict__ ITr){
  int idx4 = blockIdx.x*256 + threadIdx.x;           // 32768 float4 lanes
  int b = idx4 >> 10, col4 = idx4 & 1023;
  float4 a = ((const float4*)bias)[col4];
  #pragma unroll 16
  for (int y=0;y<128;y++){
    float4 p = ((const float4*)(part + (long)y*131072 + (long)b*FC1_N))[col4];
    a.x+=p.x; a.y+=p.y; a.z+=p.z; a.w+=p.w;
  }
  int col = col4*4;
  ITr[(col+0)*32 + b] = a.x;
  ITr[(col+1)*32 + b] = a.y;
  ITr[(col+2)*32 + b] = a.z;
  ITr[(col+3)*32 + b] = a.w;
}

// ---- reduce fc2 partials (64) + bias + permuted write to out[b][o][n] ----------
__global__ void k_red2(const float* __restrict__ part, const float* __restrict__ bias,
                       float* __restrict__ outp){
  int idx4 = blockIdx.x*256 + threadIdx.x;           // 32768 float4 lanes
  int b = idx4 >> 10, col4 = idx4 & 1023;
  float4 a = ((const float4*)bias)[col4];
  #pragma unroll 16
  for (int y=0;y<64;y++){
    float4 p = ((const float4*)(part + (long)y*131072 + (long)b*FC1_N))[col4];
    a.x+=p.x; a.y+=p.y; a.z+=p.z; a.w+=p.w;
  }
  float av[4] = {a.x, a.y, a.z, a.w};
  #pragma unroll
  for (int c=0;c<4;c++){
    int col = col4*4 + c;
    int n = col >> 4, o = col & 15;
    outp[(b<<12) + (o<<8) + n] = av[c];
  }
}

extern "C" void kernel_launch(void* const* d_in, const int* in_sizes, int n_in,
                              void* d_out, int out_size, void* d_ws, size_t ws_size,
                              hipStream_t stream) {
  const float* data   = (const float*)d_in[0];
  const unsigned char* masks = (const unsigned char*)d_in[1];
  const int* ei       = (const int*)d_in[2];
  const float* gcn_w  = (const float*)d_in[3];
  const float* gcn_b  = (const float*)d_in[4];
  const float* sa_qw  = (const float*)d_in[5];
  const float* sa_qb  = (const float*)d_in[6];
  const float* sa_kw  = (const float*)d_in[7];
  const float* sa_kb  = (const float*)d_in[8];
  const float* wih    = (const float*)d_in[9];
  const float* whh    = (const float*)d_in[10];
  const float* bih    = (const float*)d_in[11];
  const float* bhh    = (const float*)d_in[12];
  const float* ta_qw  = (const float*)d_in[13];
  const float* ta_qb  = (const float*)d_in[14];
  const float* ta_kw  = (const float*)d_in[15];
  const float* ta_kb  = (const float*)d_in[16];
  const float* fc1_w  = (const float*)d_in[17];
  const float* fc1_b  = (const float*)d_in[18];
  const float* fc2_w  = (const float*)d_in[19];
  const float* fc2_b  = (const float*)d_in[20];

  float* dm    = (float*)d_ws;        // 131072
  float* wadj  = dm + 131072;         // 65536
  int*   flags = (int*)(wadj + 65536);// 8
  float* xw    = (float*)(flags + 8); // 524288
  float* hb    = xw + 524288;
  float* qb    = hb + 524288;
  float* kb    = qb + 524288;
  float* rnn   = kb + 524288;
  float* qt    = rnn + 524288;
  float* kt    = qt + 524288;
  float* ET    = kt + 524288;         // 1048576
  float* ITr   = ET + 1048576;        // 131072
  float* part1 = ITr + 131072;        // 128*131072
  float* part2 = part1 + 128*131072;  // 64*131072

  float* out_final = (float*)d_out;
  float* out_sa = out_final + 131072;
  float* out_ra = out_final + 655360;

  hipMemsetAsync(flags, 0, 32, stream);

  k_detect<<<128,256,0,stream>>>(masks, ei, flags);
  k_mask<<<512,256,0,stream>>>(data, masks, flags, dm);
  k_graph<<<1,256,0,stream>>>(ei, flags, wadj);
  k_xw<<<2048,256,0,stream>>>(dm, gcn_w, xw);
  k_gru<12><<<32,192,0,stream>>>(dm, wih, bih, whh, bhh, rnn);   // DIAG x12
  k_agg<<<2048,256,0,stream>>>(wadj, xw, gcn_b, hb);
  k_qk2<<<4096,256,0,stream>>>(hb, rnn, sa_qw, sa_qb, sa_kw, sa_kb,
                               ta_qw, ta_qb, ta_kw, ta_kb, qb, kb, qt, kt);
  k_attn2<40><<<2048,256,0,stream>>>(qb, kb, hb, qt, kt, rnn, out_sa, out_ra); // DIAG x40
  k_embedT<<<4096,256,0,stream>>>(rnn, hb, ET);
  { dim3 g(8,128); k_fc<256,4><<<g,512,0,stream>>>(fc1_w, ET, part1); }        // DIAG x4
  k_red1<<<128,256,0,stream>>>(part1, fc1_b, ITr);
  { dim3 g(8,64); k_fc<64,1><<<g,512,0,stream>>>(fc2_w, ITr, part2); }
  k_red2<<<128,256,0,stream>>>(part2, fc2_b, out_final);
}

// Round 8
// 531.771 us; speedup vs baseline: 7.1743x; 7.1743x over previous
//
#include <hip/hip_runtime.h>

#define NB 32
#define NN 256
#define NI 16
#define NO 16
#define NC 64
#define NH 64
#define NE 4096
#define FC1_N 4096

__device__ __forceinline__ float sigmoidf_(float x){ return 1.0f/(1.0f+__expf(-x)); }
__device__ __forceinline__ float tanhf_(float x){
  float e = __expf(2.0f*x);
  return 1.0f - 2.0f/(e+1.0f);
}

// async global->LDS, 16B per lane (lane i lands at ldsbase + i*16)
__device__ __forceinline__ void gload16(const void* g, void* l){
  __builtin_amdgcn_global_load_lds((const __attribute__((address_space(1))) void*)g,
                                   (__attribute__((address_space(3))) void*)l, 16, 0, 0);
}

// ---- runtime dtype detection ------------------------------------------------
__global__ void k_detect(const unsigned char* __restrict__ m8, const int* __restrict__ ei, int* flags){
  int t = blockIdx.x*256 + threadIdx.x;              // 32768 threads
  unsigned a = (unsigned)m8[t*4+1] | (unsigned)m8[t*4+2] | (unsigned)m8[t*4+3];
  if (__any(a != 0) && (threadIdx.x & 63) == 0) atomicOr(&flags[0], 1);
  unsigned b = 0;
  if (t < 4096) b = (unsigned)ei[2*t+1];
  if (__any(b != 0) && (threadIdx.x & 63) == 0) atomicOr(&flags[1], 1);
}

// ---- mask -------------------------------------------------------------------
__global__ void k_mask(const float* __restrict__ data, const unsigned char* __restrict__ m8,
                       const int* __restrict__ flags, float* __restrict__ dm){
  int i = blockIdx.x*256 + threadIdx.x;              // 131072
  int mv = flags[0] ? (int)m8[i] : ((const int*)m8)[i];
  dm[i] = mv ? data[i] : 0.0f;
}

__device__ __forceinline__ int edge_src(const int* ei, const int* flags, int e){
  return flags[1] ? ei[e] : ei[2*e];
}
__device__ __forceinline__ int edge_dst(const int* ei, const int* flags, int e){
  return flags[1] ? ei[NE + e] : ei[2*(NE + e)];
}

// ---- GCN graph prep: zero wadj, degree, dinv, weighted adjacency (one block) --
__global__ __launch_bounds__(256) void k_graph(const int* __restrict__ ei, const int* __restrict__ flags,
                                               float* wadj){
  int t = threadIdx.x;
  float4 z = {0.f,0.f,0.f,0.f};
  for (int x = t; x < 16384; x += 256) ((float4*)wadj)[x] = z;
  __shared__ float degs[NN];
  __shared__ float dls[NN];
  degs[t] = 0.f;
  __syncthreads();
  for (int e = t; e < NE; e += 256) atomicAdd(&degs[edge_dst(ei, flags, e)], 1.0f);
  __syncthreads();
  float di = rsqrtf(degs[t] + 2.0f);
  dls[t] = di;
  atomicAdd(&wadj[t*NN + t], 2.0f*di*di);
  __syncthreads();
  for (int e = t; e < NE; e += 256){
    int s = edge_src(ei, flags, e), d = edge_dst(ei, flags, e);
    atomicAdd(&wadj[d*NN + s], dls[s]*dls[d]);
  }
}

// ---- xw = x @ gcn_w ----------------------------------------------------------
__global__ void k_xw(const float* __restrict__ dm, const float* __restrict__ gw, float* __restrict__ xw){
  int idx = blockIdx.x*256 + threadIdx.x;            // 524288
  int c = idx & 63, n = (idx>>6) & 255, b = idx>>14;
  const float* dmb = dm + b*NI*NN;
  float a = 0.f;
  #pragma unroll
  for (int i=0;i<NI;i++) a += dmb[i*NN + n]*gw[i*NC + c];
  xw[idx] = a;
}

// ---- h = relu(W_adj @ xw + b) -------------------------------------------------
__global__ void k_agg(const float* __restrict__ wadj, const float* __restrict__ xw,
                      const float* __restrict__ gb, float* __restrict__ h){
  int idx = blockIdx.x*256 + threadIdx.x;            // 524288
  int c = idx & 63, n = (idx>>6) & 255, b = idx>>14;
  const float* wr = wadj + n*NN;
  const float* xb = xw + b*NN*NC + c;
  float a = gb[c];
  #pragma unroll 4
  for (int m=0;m<NN;m++) a += wr[m]*xb[m*NC];
  h[idx] = fmaxf(a, 0.0f);
}

// ---- q,k projections, spatial (blocks<2048) + temporal fused -------------------
__global__ void k_qk2(const float* __restrict__ hb, const float* __restrict__ rnn,
    const float* __restrict__ saqw, const float* __restrict__ saqb,
    const float* __restrict__ sakw, const float* __restrict__ sakb,
    const float* __restrict__ taqw, const float* __restrict__ taqb,
    const float* __restrict__ takw, const float* __restrict__ takb,
    float* __restrict__ qb, float* __restrict__ kb, float* __restrict__ qt, float* __restrict__ kt){
  int bid = blockIdx.x;
  const float *src, *qw, *qbias, *kw, *kbias; float *qo, *ko;
  if (bid < 2048){ src=hb; qw=saqw; qbias=saqb; kw=sakw; kbias=sakb; qo=qb; ko=kb; }
  else { bid -= 2048; src=rnn; qw=taqw; qbias=taqb; kw=takw; kbias=takb; qo=qt; ko=kt; }
  int idx = bid*256 + threadIdx.x;
  int c = idx & 63;
  const float* hr = src + (idx>>6)*NC;
  float aq = qbias[c], ak = kbias[c];
  #pragma unroll 8
  for (int cc=0; cc<NC; cc++){ float hv = hr[cc]; aq += hv*qw[cc*NC + c]; ak += hv*kw[cc*NC + c]; }
  qo[idx] = aq; ko[idx] = ak;
}

// ---- fused attention pair: 8 query rows per block, transposed output write -----
__global__ __launch_bounds__(256) void k_attn2(const float* __restrict__ qb, const float* __restrict__ kb,
    const float* __restrict__ hb, const float* __restrict__ qt, const float* __restrict__ kt,
    const float* __restrict__ rnn, float* __restrict__ out_sa, float* __restrict__ out_ra){
  int bidx = blockIdx.x;
  const float *q, *kmat, *v; float* outp;
  if (bidx < 1024){ q=qb; kmat=kb; v=hb; outp=out_sa; }
  else { bidx -= 1024; q=qt; kmat=kt; v=rnn; outp=out_ra; }
  int b = bidx >> 5, n0 = (bidx & 31)*8;
  int t = threadIdx.x;
  const float scale = 0.0625f;
  __shared__ __align__(16) float qs[8][64];
  __shared__ float S[8][256];
  #pragma unroll
  for (int rp2=0; rp2<2; rp2++){
    int j = rp2*256 + t; int r = j>>6, c = j&63;
    qs[r][c] = q[((b<<8) + n0 + r)*NC + c];
  }
  __syncthreads();
  float4 kr[16];
  const float4* kp = (const float4*)(kmat + ((b<<8) + t)*NC);
  #pragma unroll
  for (int i=0;i<16;i++) kr[i] = kp[i];
  #pragma unroll
  for (int r=0;r<8;r++){
    const float4* q4 = (const float4*)qs[r];
    float s = 0.f;
    #pragma unroll
    for (int i=0;i<16;i++){ float4 a=q4[i], bb=kr[i]; s += a.x*bb.x + a.y*bb.y + a.z*bb.z + a.w*bb.w; }
    S[r][t] = s*scale;
  }
  __syncthreads();
  {
    int g = t>>5, l = t&31;
    float vals[8];
    #pragma unroll
    for (int k2=0;k2<8;k2++) vals[k2] = S[g][l + (k2<<5)];
    float mx = vals[0];
    #pragma unroll
    for (int k2=1;k2<8;k2++) mx = fmaxf(mx, vals[k2]);
    #pragma unroll
    for (int off=16; off; off>>=1) mx = fmaxf(mx, __shfl_xor(mx, off));
    float sm = 0.f;
    #pragma unroll
    for (int k2=0;k2<8;k2++){ vals[k2] = __expf(vals[k2]-mx); sm += vals[k2]; }
    #pragma unroll
    for (int off=16; off; off>>=1) sm += __shfl_xor(sm, off);
    float rS = 1.0f/sm;
    #pragma unroll
    for (int k2=0;k2<8;k2++) S[g][l + (k2<<5)] = vals[k2]*rS;
  }
  __syncthreads();
  int c = t & 63, rp = t >> 6;
  const float* vp = v + (b<<8)*NC + c;
  float a0 = 0.f, a1 = 0.f;
  #pragma unroll 4
  for (int m=0;m<NN;m++){
    float vv = vp[m*NC];
    a0 += S[rp][m]*vv;
    a1 += S[rp+4][m]*vv;
  }
  outp[(((b<<6)+c)<<8) + n0 + rp]     = a0;
  outp[(((b<<6)+c)<<8) + n0 + rp + 4] = a1;
}

// ---- GRU: 3 waves (r/z/n rows), ONE barrier per step ---------------------------
// ghB double-buffered by step parity (waves stay within 1 barrier of each other,
// so write[t+1] into buffer p^1 never collides with read[t] from buffer p).
// Each wave keeps its OWN copy of h in hsW[w] (written redundantly by all waves;
// same-wave ds_write->ds_read ordering replaces the second barrier).
__global__ __launch_bounds__(192) void k_gru(const float* __restrict__ dm,
        const float* __restrict__ wih, const float* __restrict__ bih,
        const float* __restrict__ whh, const float* __restrict__ bhh,
        float* __restrict__ rnn){
  const int b = blockIdx.x, j = threadIdx.x;
  const int w = j >> 6, lane = j & 63;
  __shared__ __align__(16) float dmS[4096];
  __shared__ float ghB[2][192];
  __shared__ float giB[2][64];
  __shared__ __align__(16) float hsW[3][64];
  float wh[64];
  const float4* wr = (const float4*)(whh + (long)j*NH);
  #pragma unroll
  for (int k4=0;k4<16;k4++){ float4 t4 = wr[k4]; wh[4*k4]=t4.x; wh[4*k4+1]=t4.y; wh[4*k4+2]=t4.z; wh[4*k4+3]=t4.w; }
  float wi[16];
  const float4* wir = (const float4*)(wih + (long)j*NI);
  #pragma unroll
  for (int k4=0;k4<4;k4++){ float4 t4 = wir[k4]; wi[4*k4]=t4.x; wi[4*k4+1]=t4.y; wi[4*k4+2]=t4.z; wi[4*k4+3]=t4.w; }
  const float bjh = bhh[j], bji = bih[j];
  const float4* dmb4 = (const float4*)(dm + b*4096);
  for (int x = j; x < 1024; x += 192) ((float4*)dmS)[x] = dmb4[x];
  hsW[w][lane] = 0.f;
  float hprev = 0.f;
  __syncthreads();                                   // dmS ready
  float* rp = rnn + (long)b*NN*NH;
  for (int t=0;t<NN;t++){
    const int p = t & 1;
    // matvec against own h copy (uniform b128 reads -> broadcast, conflict-free)
    float a0=0.f,a1=0.f,a2=0.f,a3=0.f;
    const float4* hp = (const float4*)hsW[w];
    #pragma unroll
    for (int k4=0;k4<16;k4++){
      float4 hv = hp[k4];
      a0 += wh[4*k4+0]*hv.x; a1 += wh[4*k4+1]*hv.y; a2 += wh[4*k4+2]*hv.z; a3 += wh[4*k4+3]*hv.w;
    }
    float gh = a0+a1+a2+a3 + bjh;
    const float* xt = &dmS[t*16];
    float gi = bji;
    #pragma unroll
    for (int i=0;i<16;i++) gi += wi[i]*xt[i];
    if (w < 2) ghB[p][j] = gh + gi;                   // r,z: input+hidden combined
    else { ghB[p][j] = gh; giB[p][lane] = gi; }      // n: keep split (r gates hidden part)
    __syncthreads();                                 // the ONLY barrier per step
    float rr = sigmoidf_(ghB[p][lane]);
    float zz = sigmoidf_(ghB[p][lane+64]);
    float nn2 = tanhf_(giB[p][lane] + rr*ghB[p][lane+128]);
    float hn = nn2 + zz*(hprev - nn2);
    hprev = hn;
    hsW[w][lane] = hn;                               // own copy; same-wave ordering
    if (w == 0) rp[t*NH + lane] = hn;
  }
}

// ---- E_T[32768][32]: transposed embed = concat([rnn_out, se]) ------------------
__global__ void k_embedT(const float* __restrict__ rnn, const float* __restrict__ h,
                         float* __restrict__ ET){
  int idx = blockIdx.x*256 + threadIdx.x;            // 1048576
  int bb = idx & 31, rr = idx >> 5;
  int n = rr >> 7, c = rr & 127;
  float v;
  if (c < 64) v = rnn[((bb<<8) + n)*NH + c];
  else { int f = (n<<6) + (c-64); v = h[(bb<<14) + ((f&255)<<6) + (f>>8)]; }
  ET[idx] = v;
}

// ---- fc GEMM: 4 waves = 2 col-waves x 2 batch-halves; CT=4 cols x 16 batches ---
// One ds_read_b128 per 64 FMAs; E via uniform (readfirstlane-scalarized) loads
// with 1-row lookahead -> no E in LDS. chunk = 8 rows x 512 cols = 16 KB, dbuf.
#define FM4(q, ee) { \
  acc[0][4*q+0]+=w4.x*ee.x; acc[1][4*q+0]+=w4.y*ee.x; acc[2][4*q+0]+=w4.z*ee.x; acc[3][4*q+0]+=w4.w*ee.x; \
  acc[0][4*q+1]+=w4.x*ee.y; acc[1][4*q+1]+=w4.y*ee.y; acc[2][4*q+1]+=w4.z*ee.y; acc[3][4*q+1]+=w4.w*ee.y; \
  acc[0][4*q+2]+=w4.x*ee.z; acc[1][4*q+2]+=w4.y*ee.z; acc[2][4*q+2]+=w4.z*ee.z; acc[3][4*q+2]+=w4.w*ee.z; \
  acc[0][4*q+3]+=w4.x*ee.w; acc[1][4*q+3]+=w4.y*ee.w; acc[2][4*q+3]+=w4.z*ee.w; acc[3][4*q+3]+=w4.w*ee.w; }

template<int KC>
__global__ __launch_bounds__(256, 2) void k_fc(const float* __restrict__ W,
        const float* __restrict__ Ein, float* __restrict__ part){
  const int tid = threadIdx.x, lane = tid & 63, wv_ = tid >> 6;
  const int cw = wv_ & 1;
  const int bqu = __builtin_amdgcn_readfirstlane(wv_ >> 1);   // uniform batch-half
  const int c0 = blockIdx.x*512;
  const long k0 = (long)blockIdx.y*KC;
  __shared__ __align__(16) float wlds[2][8][512];    // 32 KB double-buffered W
  float acc[4][16];
  #pragma unroll
  for (int c=0;c<4;c++)
    #pragma unroll
    for (int bb=0;bb<16;bb++) acc[c][bb]=0.f;

  const int NCH = KC/8;
  // wave wv_ stages rows {2wv_, 2wv_+1}: 4 gload16
  #define STAGE_FC(ch, bf) { \
    const float* ws = W + (k0 + (long)(ch)*8 + 2*wv_)*FC1_N + c0; \
    gload16(ws + lane*4,               &wlds[bf][2*wv_][0]); \
    gload16(ws + 256 + lane*4,         &wlds[bf][2*wv_][256]); \
    gload16(ws + FC1_N + lane*4,       &wlds[bf][2*wv_+1][0]); \
    gload16(ws + FC1_N + 256 + lane*4, &wlds[bf][2*wv_+1][256]); \
  }

  STAGE_FC(0, 0)
  int cur = 0;
  for (int ch=0; ch<NCH; ch++){
    __syncthreads();                                  // chunk ch ready (vmcnt drain at barrier)
    if (ch+1 < NCH) STAGE_FC(ch+1, cur^1)
    const float* ep = Ein + (k0 + (long)ch*8)*32 + bqu*16;  // uniform pointer
    float4 E0 = *(const float4*)(ep+0),  E1 = *(const float4*)(ep+4);
    float4 E2 = *(const float4*)(ep+8),  E3 = *(const float4*)(ep+12);
    #pragma unroll
    for (int r=0;r<8;r++){
      float4 C0=E0, C1=E1, C2=E2, C3=E3;
      if (r < 7){
        const float* en = ep + (r+1)*32;
        E0 = *(const float4*)(en+0);  E1 = *(const float4*)(en+4);
        E2 = *(const float4*)(en+8);  E3 = *(const float4*)(en+12);
      }
      float4 w4 = *(const float4*)&wlds[cur][r][cw*256 + lane*4];
      FM4(0, C0) FM4(1, C1) FM4(2, C2) FM4(3, C3)
    }
    cur ^= 1;
  }
  float* pp = part + (long)blockIdx.y*131072 + (long)(bqu*16)*FC1_N + c0 + cw*256 + lane*4;
  #pragma unroll
  for (int bb=0;bb<16;bb++){
    float4 o; o.x=acc[0][bb]; o.y=acc[1][bb]; o.z=acc[2][bb]; o.w=acc[3][bb];
    *(float4*)(pp + (long)bb*FC1_N) = o;
  }
  #undef STAGE_FC
}

// ---- reduce fc1 partials (64) + bias -> interT[4096][32] ----------------------
__global__ void k_red1(const float* __restrict__ part, const float* __restrict__ bias,
                       float* __restrict__ ITr){
  int idx4 = blockIdx.x*256 + threadIdx.x;           // 32768 float4 lanes
  int b = idx4 >> 10, col4 = idx4 & 1023;
  float4 a = ((const float4*)bias)[col4];
  #pragma unroll 16
  for (int y=0;y<64;y++){
    float4 p = ((const float4*)(part + (long)y*131072 + (long)b*FC1_N))[col4];
    a.x+=p.x; a.y+=p.y; a.z+=p.z; a.w+=p.w;
  }
  int col = col4*4;
  ITr[(col+0)*32 + b] = a.x;
  ITr[(col+1)*32 + b] = a.y;
  ITr[(col+2)*32 + b] = a.z;
  ITr[(col+3)*32 + b] = a.w;
}

// ---- reduce fc2 partials (64) + bias + permuted write to out[b][o][n] ----------
__global__ void k_red2(const float* __restrict__ part, const float* __restrict__ bias,
                       float* __restrict__ outp){
  int idx4 = blockIdx.x*256 + threadIdx.x;           // 32768 float4 lanes
  int b = idx4 >> 10, col4 = idx4 & 1023;
  float4 a = ((const float4*)bias)[col4];
  #pragma unroll 16
  for (int y=0;y<64;y++){
    float4 p = ((const float4*)(part + (long)y*131072 + (long)b*FC1_N))[col4];
    a.x+=p.x; a.y+=p.y; a.z+=p.z; a.w+=p.w;
  }
  float av[4] = {a.x, a.y, a.z, a.w};
  #pragma unroll
  for (int c=0;c<4;c++){
    int col = col4*4 + c;
    int n = col >> 4, o = col & 15;
    outp[(b<<12) + (o<<8) + n] = av[c];
  }
}

extern "C" void kernel_launch(void* const* d_in, const int* in_sizes, int n_in,
                              void* d_out, int out_size, void* d_ws, size_t ws_size,
                              hipStream_t stream) {
  const float* data   = (const float*)d_in[0];
  const unsigned char* masks = (const unsigned char*)d_in[1];
  const int* ei       = (const int*)d_in[2];
  const float* gcn_w  = (const float*)d_in[3];
  const float* gcn_b  = (const float*)d_in[4];
  const float* sa_qw  = (const float*)d_in[5];
  const float* sa_qb  = (const float*)d_in[6];
  const float* sa_kw  = (const float*)d_in[7];
  const float* sa_kb  = (const float*)d_in[8];
  const float* wih    = (const float*)d_in[9];
  const float* whh    = (const float*)d_in[10];
  const float* bih    = (const float*)d_in[11];
  const float* bhh    = (const float*)d_in[12];
  const float* ta_qw  = (const float*)d_in[13];
  const float* ta_qb  = (const float*)d_in[14];
  const float* ta_kw  = (const float*)d_in[15];
  const float* ta_kb  = (const float*)d_in[16];
  const float* fc1_w  = (const float*)d_in[17];
  const float* fc1_b  = (const float*)d_in[18];
  const float* fc2_w  = (const float*)d_in[19];
  const float* fc2_b  = (const float*)d_in[20];

  float* dm    = (float*)d_ws;        // 131072
  float* wadj  = dm + 131072;         // 65536
  int*   flags = (int*)(wadj + 65536);// 8
  float* xw    = (float*)(flags + 8); // 524288
  float* hb    = xw + 524288;
  float* qb    = hb + 524288;
  float* kb    = qb + 524288;
  float* rnn   = kb + 524288;
  float* qt    = rnn + 524288;
  float* kt    = qt + 524288;
  float* ET    = kt + 524288;         // 1048576
  float* ITr   = ET + 1048576;        // 131072
  float* part1 = ITr + 131072;        // 64*131072
  float* part2 = part1 + 64*131072;   // 64*131072

  float* out_final = (float*)d_out;
  float* out_sa = out_final + 131072;
  float* out_ra = out_final + 655360;

  hipMemsetAsync(flags, 0, 32, stream);

  k_detect<<<128,256,0,stream>>>(masks, ei, flags);
  k_mask<<<512,256,0,stream>>>(data, masks, flags, dm);
  k_gru<<<32,192,0,stream>>>(dm, wih, bih, whh, bhh, rnn);
  k_graph<<<1,256,0,stream>>>(ei, flags, wadj);
  k_xw<<<2048,256,0,stream>>>(dm, gcn_w, xw);
  k_agg<<<2048,256,0,stream>>>(wadj, xw, gcn_b, hb);
  k_qk2<<<4096,256,0,stream>>>(hb, rnn, sa_qw, sa_qb, sa_kw, sa_kb,
                               ta_qw, ta_qb, ta_kw, ta_kb, qb, kb, qt, kt);
  k_attn2<<<2048,256,0,stream>>>(qb, kb, hb, qt, kt, rnn, out_sa, out_ra);
  k_embedT<<<4096,256,0,stream>>>(rnn, hb, ET);
  { dim3 g(8,64); k_fc<512><<<g,256,0,stream>>>(fc1_w, ET, part1); }
  k_red1<<<128,256,0,stream>>>(part1, fc1_b, ITr);
  { dim3 g(8,64); k_fc<64><<<g,256,0,stream>>>(fc2_w, ITr, part2); }
  k_red2<<<128,256,0,stream>>>(part2, fc2_b, out_final);
}